// Round 5
// baseline (244.715 us; speedup 1.0000x reference)
//
#include <hip/hip_runtime.h>

// CARAFE fused: N=8, C=256, H=W=64, UP=2, K=3 -> out (8,256,128,128) fp32
// One kernel per (n, row): encoder (1x1 conv -> BN/ReLU -> 1x1 conv -> BN/ReLU
// -> softmax over k2) entirely in LDS/registers, then reassembly of all 256
// channels for that row. wts never touches global memory.

#define EPS_BN 1e-5f

typedef float f32x4 __attribute__((ext_vector_type(4)));

__global__ __launch_bounds__(256) void carafe_fused(
    const float* __restrict__ x,
    const float* __restrict__ w0, const float* __restrict__ b0,
    const float* __restrict__ g0, const float* __restrict__ be0,
    const float* __restrict__ m0, const float* __restrict__ v0,
    const float* __restrict__ w1, const float* __restrict__ b1,
    const float* __restrict__ g1, const float* __restrict__ be1,
    const float* __restrict__ m1, const float* __restrict__ v1,
    float* __restrict__ out)
{
    __shared__ float xs[256 * 64];  // [c][w] x row, 64 KB, alive through phase 2
    __shared__ float ys[64 * 64];   // [o][w] 16 KB; reused as ws[36][64] in phase 2

    const int tid = threadIdx.x;
    const int n   = blockIdx.x >> 6;     // 0..7
    const int hh  = blockIdx.x & 63;     // row
    const int w   = tid & 63;            // pixel col (lane)
    const int og  = __builtin_amdgcn_readfirstlane(tid >> 6);  // wave id 0..3

    // ---- stage x[n, :, hh, :] -> xs (vectorized, coalesced) ----
    {
        const f32x4* xg = reinterpret_cast<const f32x4*>(x + (n * 256) * 4096 + hh * 64);
        f32x4* xl = reinterpret_cast<f32x4*>(xs);
#pragma unroll
        for (int k = 0; k < 16; ++k) {
            const int i  = tid + k * 256;      // 0..4095
            const int cc = i >> 4;             // channel
            const int c4 = i & 15;             // float4 within row
            xl[cc * 16 + c4] = xg[cc * 1024 + c4];
        }
    }
    __syncthreads();

    // ---- layer0: y[o][w], o = og*16 + j. Weights via wave-uniform (SGPR) loads. ----
    float acc[16];
#pragma unroll
    for (int j = 0; j < 16; ++j) acc[j] = 0.f;

    const float* w0p = w0 + og * 16 * 256;   // row-major [16][256], uniform base
#pragma unroll 8
    for (int c = 0; c < 256; ++c) {
        const float xv = xs[c * 64 + w];
#pragma unroll
        for (int j = 0; j < 16; ++j)
            acc[j] = fmaf(xv, w0p[j * 256 + c], acc[j]);
    }

    // BN0 + ReLU -> ys
#pragma unroll
    for (int j = 0; j < 16; ++j) {
        const int o = og * 16 + j;
        const float sc = g0[o] * rsqrtf(v0[o] + EPS_BN);
        const float sh = (b0[o] - m0[o]) * sc + be0[o];
        ys[o * 64 + w] = fmaxf(fmaf(acc[j], sc, sh), 0.f);
    }
    __syncthreads();

    // ---- layer1: enc[p][w], p = kk*4 + u, u = og (uniform). ----
    float e9[9];
#pragma unroll
    for (int kk = 0; kk < 9; ++kk) e9[kk] = 0.f;
    const int u = og;
    const float* w1p = w1 + u * 64;          // w1[(kk*4+u)*64 + o] = w1p[kk*256 + o]
#pragma unroll 4
    for (int o = 0; o < 64; ++o) {
        const float yv = ys[o * 64 + w];
#pragma unroll
        for (int kk = 0; kk < 9; ++kk)
            e9[kk] = fmaf(yv, w1p[kk * 256 + o], e9[kk]);
    }

    // BN1 + ReLU, softmax over kk (in-register)
    float mx = -1e30f;
#pragma unroll
    for (int kk = 0; kk < 9; ++kk) {
        const int p = kk * 4 + u;
        const float sc = g1[p] * rsqrtf(v1[p] + EPS_BN);
        const float sh = (b1[p] - m1[p]) * sc + be1[p];
        float e = fmaxf(fmaf(e9[kk], sc, sh), 0.f);
        e9[kk] = e;
        mx = fmaxf(mx, e);
    }
    float s = 0.f;
#pragma unroll
    for (int kk = 0; kk < 9; ++kk) {
        e9[kk] = __expf(e9[kk] - mx);
        s += e9[kk];
    }
    const float inv = 1.f / s;

    __syncthreads();                 // all ys reads done; safe to overwrite as ws
    float* ws = ys;                  // ws[p][w], p = kk*4 + u
#pragma unroll
    for (int kk = 0; kk < 9; ++kk)
        ws[(kk * 4 + u) * 64 + w] = e9[kk] * inv;
    __syncthreads();

    // ---- phase 2: reassemble row hh for all 256 channels ----
    // thread: pixel w, channels q*64 .. q*64+63. wt held in VGPRs.
    const int q = og;                // uniform 0..3
    float wt[36];
#pragma unroll
    for (int p = 0; p < 36; ++p) wt[p] = ws[p * 64 + w];  // 2 lanes/bank: free

    const bool hm = (hh > 0), hp = (hh < 63);
    const bool wm = (w > 0),  wp = (w < 63);

    for (int c = 0; c < 64; ++c) {
        const int cc = q * 64 + c;
        const float* xgm = x + ((n * 256 + cc) * 64 + (hh - 1)) * 64;  // row hh-1
        const float* xgp = x + ((n * 256 + cc) * 64 + (hh + 1)) * 64;  // row hh+1
        const float* xls = xs + cc * 64;                               // row hh (LDS)

        float a0 = 0.f, a1 = 0.f, a2 = 0.f, a3 = 0.f;  // u = 0..3

        // dh = -1 (k = 0,1,2) from global
        {
            const float xv0 = (hm & wm) ? xgm[w - 1] : 0.f;
            const float xv1 = hm        ? xgm[w]     : 0.f;
            const float xv2 = (hm & wp) ? xgm[w + 1] : 0.f;
            a0 = fmaf(xv0, wt[0],  fmaf(xv1, wt[4],  xv2 * wt[8]));
            a1 = fmaf(xv0, wt[1],  fmaf(xv1, wt[5],  xv2 * wt[9]));
            a2 = fmaf(xv0, wt[2],  fmaf(xv1, wt[6],  xv2 * wt[10]));
            a3 = fmaf(xv0, wt[3],  fmaf(xv1, wt[7],  xv2 * wt[11]));
        }
        // dh = 0 (k = 3,4,5) from LDS
        {
            const float xv0 = wm ? xls[w - 1] : 0.f;
            const float xv1 = xls[w];
            const float xv2 = wp ? xls[w + 1] : 0.f;
            a0 = fmaf(xv0, wt[12], fmaf(xv1, wt[16], fmaf(xv2, wt[20], a0)));
            a1 = fmaf(xv0, wt[13], fmaf(xv1, wt[17], fmaf(xv2, wt[21], a1)));
            a2 = fmaf(xv0, wt[14], fmaf(xv1, wt[18], fmaf(xv2, wt[22], a2)));
            a3 = fmaf(xv0, wt[15], fmaf(xv1, wt[19], fmaf(xv2, wt[23], a3)));
        }
        // dh = +1 (k = 6,7,8) from global
        {
            const float xv0 = (hp & wm) ? xgp[w - 1] : 0.f;
            const float xv1 = hp        ? xgp[w]     : 0.f;
            const float xv2 = (hp & wp) ? xgp[w + 1] : 0.f;
            a0 = fmaf(xv0, wt[24], fmaf(xv1, wt[28], fmaf(xv2, wt[32], a0)));
            a1 = fmaf(xv0, wt[25], fmaf(xv1, wt[29], fmaf(xv2, wt[33], a1)));
            a2 = fmaf(xv0, wt[26], fmaf(xv1, wt[30], fmaf(xv2, wt[34], a2)));
            a3 = fmaf(xv0, wt[27], fmaf(xv1, wt[31], fmaf(xv2, wt[35], a3)));
        }

        float* op = out + ((n * 256 + cc) * 128 + 2 * hh) * 128 + 2 * w;
        float2 r0; r0.x = a0; r0.y = a1;   // row 2h   : (u=0,u=1)
        float2 r1; r1.x = a2; r1.y = a3;   // row 2h+1 : (u=2,u=3)
        *reinterpret_cast<float2*>(op)       = r0;   // 512 B contiguous per wave
        *reinterpret_cast<float2*>(op + 128) = r1;
    }
}

extern "C" void kernel_launch(void* const* d_in, const int* in_sizes, int n_in,
                              void* d_out, int out_size, void* d_ws, size_t ws_size,
                              hipStream_t stream)
{
    const float* x   = (const float*)d_in[0];
    const float* w0  = (const float*)d_in[1];
    const float* b0  = (const float*)d_in[2];
    const float* g0  = (const float*)d_in[3];
    const float* be0 = (const float*)d_in[4];
    const float* m0  = (const float*)d_in[5];
    const float* v0  = (const float*)d_in[6];
    const float* w1  = (const float*)d_in[7];
    const float* b1  = (const float*)d_in[8];
    const float* g1  = (const float*)d_in[9];
    const float* be1 = (const float*)d_in[10];
    const float* m1  = (const float*)d_in[11];
    const float* v1  = (const float*)d_in[12];

    float* out = (float*)d_out;

    // 512 blocks (n x row), 80 KB LDS -> 2 blocks/CU, all co-resident.
    hipLaunchKernelGGL(carafe_fused, dim3(512), dim3(256), 0, stream,
                       x, w0, b0, g0, be0, m0, v0, w1, b1, g1, be1, m1, v1, out);
}

// Round 7
// 209.493 us; speedup vs baseline: 1.1681x; 1.1681x over previous
//
#include <hip/hip_runtime.h>

// CARAFE fused: N=8, C=256, H=W=64, UP=2, K=3 -> out (8,256,128,128) fp32
// One block per (n, row), 512 threads (8 waves), LDS = 16 KB (y/ws exchange only).
// x is read from global/L2 everywhere (no xs staging) -> 16 waves/CU occupancy.
// Encoder: layer0 splits 64 outputs over 8 waves (8 each, SGPR weights);
// layer1+softmax per-thread in registers; phase 2 splits 256 channels 8x32.

#define EPS_BN 1e-5f

__global__ __launch_bounds__(512, 4) void carafe_fused(
    const float* __restrict__ x,
    const float* __restrict__ w0, const float* __restrict__ b0,
    const float* __restrict__ g0, const float* __restrict__ be0,
    const float* __restrict__ m0, const float* __restrict__ v0,
    const float* __restrict__ w1, const float* __restrict__ b1,
    const float* __restrict__ g1, const float* __restrict__ be1,
    const float* __restrict__ m1, const float* __restrict__ v1,
    float* __restrict__ out)
{
    __shared__ float ys[64 * 64];   // [o][w] 16 KB; reused as ws[36][64] later

    const int tid = threadIdx.x;
    const int n   = blockIdx.x >> 6;     // 0..7
    const int hh  = blockIdx.x & 63;     // row
    const int w   = tid & 63;            // pixel col (lane)
    const int og  = __builtin_amdgcn_readfirstlane(tid >> 6);  // wave id 0..7

    // ---- layer0: y[o][w], o = og*8 + j. x from global (vmcnt), weights SGPR (lgkmcnt). ----
    float acc[8];
#pragma unroll
    for (int j = 0; j < 8; ++j) acc[j] = 0.f;

    const float* xp  = x + n * 1048576 + hh * 64 + w;   // + c*4096 per channel
    const float* w0p = w0 + og * 8 * 256;               // wave-uniform base

#pragma unroll 8
    for (int c = 0; c < 256; ++c) {
        const float xv = xp[c * 4096];
#pragma unroll
        for (int j = 0; j < 8; ++j)
            acc[j] = fmaf(xv, w0p[j * 256 + c], acc[j]);
    }

    // BN0 + ReLU -> ys
#pragma unroll
    for (int j = 0; j < 8; ++j) {
        const int o = og * 8 + j;
        const float sc = g0[o] * rsqrtf(v0[o] + EPS_BN);
        const float sh = (b0[o] - m0[o]) * sc + be0[o];
        ys[o * 64 + w] = fmaxf(fmaf(acc[j], sc, sh), 0.f);
    }
    __syncthreads();

    // ---- layer1: enc[p][w], p = kk*4 + u, u = og&3 (waves 4-7 duplicate 0-3). ----
    float e9[9];
#pragma unroll
    for (int kk = 0; kk < 9; ++kk) e9[kk] = 0.f;
    const int u = og & 3;
    const float* w1p = w1 + u * 64;          // w1[(kk*4+u)*64 + o] = w1p[kk*256 + o]
#pragma unroll 8
    for (int o = 0; o < 64; ++o) {
        const float yv = ys[o * 64 + w];
#pragma unroll
        for (int kk = 0; kk < 9; ++kk)
            e9[kk] = fmaf(yv, w1p[kk * 256 + o], e9[kk]);
    }

    // BN1 + ReLU, softmax over kk (in-register)
    float mx = -1e30f;
#pragma unroll
    for (int kk = 0; kk < 9; ++kk) {
        const int p = kk * 4 + u;
        const float sc = g1[p] * rsqrtf(v1[p] + EPS_BN);
        const float sh = (b1[p] - m1[p]) * sc + be1[p];
        float e = fmaxf(fmaf(e9[kk], sc, sh), 0.f);
        e9[kk] = e;
        mx = fmaxf(mx, e);
    }
    float s = 0.f;
#pragma unroll
    for (int kk = 0; kk < 9; ++kk) {
        e9[kk] = __expf(e9[kk] - mx);
        s += e9[kk];
    }
    const float inv = 1.f / s;

    __syncthreads();                 // all ys reads done; safe to overwrite as ws
    if (og < 4) {
#pragma unroll
        for (int kk = 0; kk < 9; ++kk)
            ys[(kk * 4 + u) * 64 + w] = e9[kk] * inv;   // ws[p][w]
    }
    __syncthreads();

    // ---- phase 2: reassemble row hh; wave og handles channels og*32 .. og*32+31 ----
    float wt[36];
#pragma unroll
    for (int p = 0; p < 36; ++p) wt[p] = ys[p * 64 + w];   // 2 lanes/bank: free

    const bool hm = (hh > 0), hp = (hh < 63);
    const bool wm = (w > 0),  wp = (w < 63);
    const float* xrow = x + n * 1048576 + hh * 64;   // (n, c=0, hh, 0)

#pragma unroll 2
    for (int i = 0; i < 32; ++i) {
        const int cc = og * 32 + i;
        const float* xr = xrow + cc * 4096;          // row hh of channel cc
        const float* xm = xr - 64;                   // row hh-1
        const float* xq = xr + 64;                   // row hh+1

        float a0 = 0.f, a1 = 0.f, a2 = 0.f, a3 = 0.f;  // u = 0..3

        // dh = -1 (k = 0,1,2)
        {
            const float xv0 = (hm & wm) ? xm[w - 1] : 0.f;
            const float xv1 = hm        ? xm[w]     : 0.f;
            const float xv2 = (hm & wp) ? xm[w + 1] : 0.f;
            a0 = fmaf(xv0, wt[0],  fmaf(xv1, wt[4],  xv2 * wt[8]));
            a1 = fmaf(xv0, wt[1],  fmaf(xv1, wt[5],  xv2 * wt[9]));
            a2 = fmaf(xv0, wt[2],  fmaf(xv1, wt[6],  xv2 * wt[10]));
            a3 = fmaf(xv0, wt[3],  fmaf(xv1, wt[7],  xv2 * wt[11]));
        }
        // dh = 0 (k = 3,4,5)
        {
            const float xv0 = wm ? xr[w - 1] : 0.f;
            const float xv1 = xr[w];
            const float xv2 = wp ? xr[w + 1] : 0.f;
            a0 = fmaf(xv0, wt[12], fmaf(xv1, wt[16], fmaf(xv2, wt[20], a0)));
            a1 = fmaf(xv0, wt[13], fmaf(xv1, wt[17], fmaf(xv2, wt[21], a1)));
            a2 = fmaf(xv0, wt[14], fmaf(xv1, wt[18], fmaf(xv2, wt[22], a2)));
            a3 = fmaf(xv0, wt[15], fmaf(xv1, wt[19], fmaf(xv2, wt[23], a3)));
        }
        // dh = +1 (k = 6,7,8)
        {
            const float xv0 = (hp & wm) ? xq[w - 1] : 0.f;
            const float xv1 = hp        ? xq[w]     : 0.f;
            const float xv2 = (hp & wp) ? xq[w + 1] : 0.f;
            a0 = fmaf(xv0, wt[24], fmaf(xv1, wt[28], fmaf(xv2, wt[32], a0)));
            a1 = fmaf(xv0, wt[25], fmaf(xv1, wt[29], fmaf(xv2, wt[33], a1)));
            a2 = fmaf(xv0, wt[26], fmaf(xv1, wt[30], fmaf(xv2, wt[34], a2)));
            a3 = fmaf(xv0, wt[27], fmaf(xv1, wt[31], fmaf(xv2, wt[35], a3)));
        }

        float* op = out + ((n * 256 + cc) * 128 + 2 * hh) * 128 + 2 * w;
        float2 r0; r0.x = a0; r0.y = a1;   // row 2h   : (u=0,u=1)
        float2 r1; r1.x = a2; r1.y = a3;   // row 2h+1 : (u=2,u=3)
        *reinterpret_cast<float2*>(op)       = r0;   // 512 B contiguous per wave
        *reinterpret_cast<float2*>(op + 128) = r1;
    }
}

extern "C" void kernel_launch(void* const* d_in, const int* in_sizes, int n_in,
                              void* d_out, int out_size, void* d_ws, size_t ws_size,
                              hipStream_t stream)
{
    const float* x   = (const float*)d_in[0];
    const float* w0  = (const float*)d_in[1];
    const float* b0  = (const float*)d_in[2];
    const float* g0  = (const float*)d_in[3];
    const float* be0 = (const float*)d_in[4];
    const float* m0  = (const float*)d_in[5];
    const float* v0  = (const float*)d_in[6];
    const float* w1  = (const float*)d_in[7];
    const float* b1  = (const float*)d_in[8];
    const float* g1  = (const float*)d_in[9];
    const float* be1 = (const float*)d_in[10];
    const float* m1  = (const float*)d_in[11];
    const float* v1  = (const float*)d_in[12];

    float* out = (float*)d_out;

    // 512 blocks (n x row) x 512 threads; 16 KB LDS -> 2 blocks/CU, 16 waves/CU.
    hipLaunchKernelGGL(carafe_fused, dim3(512), dim3(512), 0, stream,
                       x, w0, b0, g0, be0, m0, v0, w1, b1, g1, be1, m1, v1, out);
}